// Round 9
// baseline (215.169 us; speedup 1.0000x reference)
//
#include <hip/hip_runtime.h>
#include <hip/hip_bf16.h>
#include <math.h>

// ---------------------------------------------------------------------------
// B=2, S=2048, E=1024, R=256, H=16, Dqk=128 (rope64|nope64), Dv=64. BS=4096.
// Round 9: sincosf -> __sincosf in rope epilogues (libcall was dominating
// gemm_qkv's rope blocks); x-cast fused into down-proj staging (fp32 A ->
// inline bf16 convert -> ds_write_b128); cast kernel now weights-only.
// Attention unchanged from round 8 (isolate variables).
// ---------------------------------------------------------------------------

typedef __attribute__((ext_vector_type(8))) short  short8;   // 8 bf16 (4 VGPR)
typedef __attribute__((ext_vector_type(4))) float  floatx4;  // MFMA C/D frag

static __device__ __forceinline__ unsigned short f2bf(float f) {
    __hip_bfloat16 h = __float2bfloat16(f);   // RNE
    return *reinterpret_cast<unsigned short*>(&h);
}

#define GLL16(gp, lp) __builtin_amdgcn_global_load_lds( \
    (const __attribute__((address_space(1))) void*)(gp), \
    (__attribute__((address_space(3))) void*)(lp), 16, 0, 0)

// ---------------------------------------------------------------------------
// fp32 -> bf16 casts, batched (8 weight tensors; x is cast in-GEMM now)
// ---------------------------------------------------------------------------
struct CastDesc { const float* src; unsigned short* dst; int n4; };
struct CastArgs { CastDesc d[8]; };

__global__ __launch_bounds__(256) void cast_bf16_multi(CastArgs a)
{
    CastDesc dd = a.d[blockIdx.y];
    const int stride = gridDim.x * 256;
    for (int i = blockIdx.x * 256 + threadIdx.x; i < dd.n4; i += stride) {
        float4 v = ((const float4*)dd.src)[i];
        ushort4 o = make_ushort4(f2bf(v.x), f2bf(v.y), f2bf(v.z), f2bf(v.w));
        ((ushort4*)dd.dst)[i] = o;
    }
}

// ---------------------------------------------------------------------------
// 64x64-tile bf16 MFMA GEMM, 2 waves (each 32x64), BK=32.
// CVTA=false: A is bf16, staged via global_load_lds.
// CVTA=true : A is fp32, staged via float4 loads + convert + ds_write_b128
//             (per-wave contiguous 16B/lane -> conflict-free).
// C = A * B^T. MODE 0: fp32 store. MODE 3: bf16 row-major store, scaled.
// B selected from {B0,B1,B2} by n0/nspan.
// ---------------------------------------------------------------------------
template<int MODE, bool CVTA>
__global__ __launch_bounds__(128) void gemm64(
    const void* __restrict__ Ain, int lda,
    const unsigned short* __restrict__ B0,
    const unsigned short* __restrict__ B1,
    const unsigned short* __restrict__ B2, int nspan, int ldb,
    void* __restrict__ Cout, int ldc, int K, float oscale)
{
    __shared__ __align__(16) unsigned short As[64 * 32];
    __shared__ __align__(16) unsigned short Bs[64 * 32];

    const int t    = threadIdx.x;
    const int w    = t >> 6;
    const int lane = t & 63;
    const int li   = lane & 15;
    const int quad = lane >> 4;
    const int m0   = blockIdx.y * 64;
    const int n0   = blockIdx.x * 64;

    const unsigned short* Bp = (n0 < nspan) ? B0 : ((n0 < 2 * nspan) ? B1 : B2);
    const int nb0 = n0 % nspan;

    const int arow = m0 + w * 32 + (lane >> 2);
    const int acol = (lane & 3) * 8;
    const unsigned short* gb = Bp + (size_t)(nb0 + w * 32 + (lane >> 2)) * ldb + acol;
    unsigned short* lA0 = &As[(w * 32) * 32];
    unsigned short* lA1 = &As[(w * 32 + 16) * 32];
    unsigned short* lB0 = &Bs[(w * 32) * 32];
    unsigned short* lB1 = &Bs[(w * 32 + 16) * 32];
    // CVTA: per-thread LDS write addresses (contiguous 16B/lane)
    unsigned short* wA0 = &As[(w * 32 + (lane >> 2)) * 32 + acol];
    unsigned short* wA1 = wA0 + 16 * 32;

    floatx4 acc[2][4];
    #pragma unroll
    for (int i = 0; i < 2; ++i)
        #pragma unroll
        for (int j = 0; j < 4; ++j)
            acc[i][j] = (floatx4){0.f, 0.f, 0.f, 0.f};

    for (int k0 = 0; k0 < K; k0 += 32) {
        if (CVTA) {
            const float* Af = (const float*)Ain;
            const float* ga0 = Af + (size_t)arow * lda + k0 + acol;
            float4 a00 = *(const float4*)(ga0);
            float4 a01 = *(const float4*)(ga0 + 4);
            float4 a10 = *(const float4*)(ga0 + (size_t)16 * lda);
            float4 a11 = *(const float4*)(ga0 + (size_t)16 * lda + 4);
            __syncthreads();
            GLL16(gb + k0,            lB0);
            GLL16(gb + 16 * ldb + k0, lB1);
            ushort4 p0 = make_ushort4(f2bf(a00.x), f2bf(a00.y), f2bf(a00.z), f2bf(a00.w));
            ushort4 p1 = make_ushort4(f2bf(a01.x), f2bf(a01.y), f2bf(a01.z), f2bf(a01.w));
            ushort4 p2 = make_ushort4(f2bf(a10.x), f2bf(a10.y), f2bf(a10.z), f2bf(a10.w));
            ushort4 p3 = make_ushort4(f2bf(a11.x), f2bf(a11.y), f2bf(a11.z), f2bf(a11.w));
            *(ushort4*)(wA0)     = p0;
            *(ushort4*)(wA0 + 4) = p1;
            *(ushort4*)(wA1)     = p2;
            *(ushort4*)(wA1 + 4) = p3;
            __syncthreads();
        } else {
            const unsigned short* Ab = (const unsigned short*)Ain;
            const unsigned short* ga = Ab + (size_t)arow * lda + acol;
            __syncthreads();
            GLL16(ga + k0,            lA0);
            GLL16(ga + 16 * lda + k0, lA1);
            GLL16(gb + k0,            lB0);
            GLL16(gb + 16 * ldb + k0, lB1);
            __syncthreads();
        }

        short8 af[2], bfr[4];
        #pragma unroll
        for (int mb = 0; mb < 2; ++mb)
            af[mb] = *(const short8*)&As[(w * 32 + mb * 16 + li) * 32 + quad * 8];
        #pragma unroll
        for (int nb = 0; nb < 4; ++nb)
            bfr[nb] = *(const short8*)&Bs[(nb * 16 + li) * 32 + quad * 8];
        #pragma unroll
        for (int mb = 0; mb < 2; ++mb)
            #pragma unroll
            for (int nb = 0; nb < 4; ++nb)
                acc[mb][nb] = __builtin_amdgcn_mfma_f32_16x16x32_bf16(
                    af[mb], bfr[nb], acc[mb][nb], 0, 0, 0);
    }

    if (MODE == 0) {
        float* C = (float*)Cout;
        #pragma unroll
        for (int mb = 0; mb < 2; ++mb)
            #pragma unroll
            for (int nb = 0; nb < 4; ++nb) {
                const int m = m0 + w * 32 + mb * 16 + quad * 4;
                const int n = n0 + nb * 16 + li;
                #pragma unroll
                for (int r = 0; r < 4; ++r)
                    C[(size_t)(m + r) * ldc + n] = acc[mb][nb][r] * oscale;
            }
    } else {
        unsigned short* C = (unsigned short*)Cout;
        #pragma unroll
        for (int mb = 0; mb < 2; ++mb)
            #pragma unroll
            for (int nb = 0; nb < 4; ++nb) {
                const int m = m0 + w * 32 + mb * 16 + quad * 4;
                const int n = n0 + nb * 16 + li;
                #pragma unroll
                for (int r = 0; r < 4; ++r)
                    C[(size_t)(m + r) * ldc + n] = f2bf(acc[mb][nb][r] * oscale);
            }
    }
}

// ---------------------------------------------------------------------------
// Fused Q/K/V up-projection GEMM. A = lat (4096 x 768, segments q|kr|kv).
// Virtual N = 5120 partitioned by n0:
//   [0,1024)    Q-rope : q_lat @ wqr^T -> rope -> Qp dims 0..63   (scaled)
//   [1024,2048) Q-nope : q_lat @ wqu^T -> Qp dims 64..127         (scaled)
//   [2048,3072) K-rope : kr_lat @ wku^T -> rope -> Kp chunk-major dims 0..63
//   [3072,4096) K-nope : kv @ wku^T -> Kp chunk-major dims 64..127
//   [4096,5120) V      : kv @ wvu^T -> Vt chunk-major
// Kp tile layout: bh*262144 + (s>>5)*4096 + (d>>3)*256 + (s&31)*8 + (d&7).
// Vt tile layout: bh*131072 + (s>>5)*2048 + ((s&31)>>3)*512 + d*8 + (s&7).
// RoPE uses fast __sincosf (HW v_sin/v_cos): arg-reduction error at s=2047
// is ~2.4e-4 rad << bf16 quantization (4e-3).
// ---------------------------------------------------------------------------
__global__ __launch_bounds__(256) void gemm_qkv(
    const unsigned short* __restrict__ lat,
    const unsigned short* __restrict__ wqr, const unsigned short* __restrict__ wqu,
    const unsigned short* __restrict__ wku, const unsigned short* __restrict__ wvu,
    unsigned short* __restrict__ Qp, unsigned short* __restrict__ Kp,
    unsigned short* __restrict__ Vt, float qscale)
{
    __shared__ __align__(16) unsigned short As[128 * 32];
    __shared__ __align__(16) unsigned short Bs[128 * 32];

    const int t    = threadIdx.x;
    const int w    = t >> 6;
    const int lane = t & 63;
    const int li   = lane & 15;
    const int quad = lane >> 4;
    const int wr   = w >> 1, wc = w & 1;
    const int m0   = blockIdx.y * 128;
    const int n0   = blockIdx.x * 128;

    const unsigned short* Ap;
    const unsigned short* Bp;
    int nloc, seg;
    if (n0 < 1024)      { seg = 0; Ap = lat;       Bp = wqr; nloc = n0; }
    else if (n0 < 2048) { seg = 1; Ap = lat;       Bp = wqu; nloc = n0 - 1024; }
    else if (n0 < 3072) { seg = 2; Ap = lat + 256; Bp = wku; nloc = n0 - 2048; }
    else if (n0 < 4096) { seg = 3; Ap = lat + 512; Bp = wku; nloc = n0 - 3072; }
    else                { seg = 4; Ap = lat + 512; Bp = wvu; nloc = n0 - 4096; }
    const float oscale = (seg <= 1) ? qscale : 1.0f;

    const unsigned short* ga = Ap + (size_t)(m0   + w * 32 + (lane >> 2)) * 768 + (lane & 3) * 8;
    const unsigned short* gb = Bp + (size_t)(nloc + w * 32 + (lane >> 2)) * 256 + (lane & 3) * 8;
    unsigned short* lA0 = &As[(w * 32) * 32];
    unsigned short* lA1 = &As[(w * 32 + 16) * 32];
    unsigned short* lB0 = &Bs[(w * 32) * 32];
    unsigned short* lB1 = &Bs[(w * 32 + 16) * 32];

    floatx4 acc[4][4];
    #pragma unroll
    for (int i = 0; i < 4; ++i)
        #pragma unroll
        for (int j = 0; j < 4; ++j)
            acc[i][j] = (floatx4){0.f, 0.f, 0.f, 0.f};

    for (int k0 = 0; k0 < 256; k0 += 32) {
        __syncthreads();
        GLL16(ga + k0,            lA0);
        GLL16(ga + 16 * 768 + k0, lA1);
        GLL16(gb + k0,            lB0);
        GLL16(gb + 16 * 256 + k0, lB1);
        __syncthreads();

        short8 af[4], bfr[4];
        #pragma unroll
        for (int mb = 0; mb < 4; ++mb)
            af[mb] = *(const short8*)&As[(wr * 64 + mb * 16 + li) * 32 + quad * 8];
        #pragma unroll
        for (int nb = 0; nb < 4; ++nb)
            bfr[nb] = *(const short8*)&Bs[(wc * 64 + nb * 16 + li) * 32 + quad * 8];
        #pragma unroll
        for (int mb = 0; mb < 4; ++mb)
            #pragma unroll
            for (int nb = 0; nb < 4; ++nb)
                acc[mb][nb] = __builtin_amdgcn_mfma_f32_16x16x32_bf16(
                    af[mb], bfr[nb], acc[mb][nb], 0, 0, 0);
    }

    const int h = ((nloc + wc * 64) >> 6) & 15;   // wave-uniform head

    if (seg == 0) {          // Q-rope -> Qp row-major dims 0..63
        float invf[2];
        #pragma unroll
        for (int nb = 0; nb < 2; ++nb)
            invf[nb] = exp2f((float)(nb * 16 + li) * -0.4152410118609203f);
        #pragma unroll
        for (int mb = 0; mb < 4; ++mb) {
            const int m = m0 + wr * 64 + mb * 16 + quad * 4;
            const int b = m >> 11, s = m & 2047;
            #pragma unroll
            for (int nb = 0; nb < 2; ++nb) {
                const int dd = nb * 16 + li;
                size_t o = ((size_t)(b * 16 + h) * 2048 + s) * 128 + dd;
                #pragma unroll
                for (int r = 0; r < 4; ++r) {
                    float ang = (float)(s + r) * invf[nb];
                    float sn, cs;
                    __sincosf(ang, &sn, &cs);
                    float x1 = acc[mb][nb][r], x2 = acc[mb][nb + 2][r];
                    Qp[o + (size_t)r * 128]      = f2bf((x1 * cs - x2 * sn) * oscale);
                    Qp[o + (size_t)r * 128 + 32] = f2bf((x2 * cs + x1 * sn) * oscale);
                }
            }
        }
    } else if (seg == 1) {   // Q-nope -> Qp row-major dims 64..127
        #pragma unroll
        for (int mb = 0; mb < 4; ++mb)
            #pragma unroll
            for (int nb = 0; nb < 4; ++nb) {
                const int m = m0 + wr * 64 + mb * 16 + quad * 4;
                const int n = nloc + wc * 64 + nb * 16 + li;
                const int dn = n & 63;
                const int b = m >> 11, s = m & 2047;
                size_t o = ((size_t)(b * 16 + h) * 2048 + s) * 128 + 64 + dn;
                #pragma unroll
                for (int r = 0; r < 4; ++r)
                    Qp[o + (size_t)r * 128] = f2bf(acc[mb][nb][r] * oscale);
            }
    } else if (seg == 2) {   // K-rope -> Kp chunk-major dims 0..63
        float invf[2];
        #pragma unroll
        for (int nb = 0; nb < 2; ++nb)
            invf[nb] = exp2f((float)(nb * 16 + li) * -0.4152410118609203f);
        #pragma unroll
        for (int mb = 0; mb < 4; ++mb) {
            const int m = m0 + wr * 64 + mb * 16 + quad * 4;
            const int b = m >> 11, sba = m & 2047;
            #pragma unroll
            for (int nb = 0; nb < 2; ++nb) {
                const int dd = nb * 16 + li;
                const int d2 = dd + 32;
                #pragma unroll
                for (int r = 0; r < 4; ++r) {
                    const int s = sba + r;
                    float ang = (float)s * invf[nb];
                    float sn, cs;
                    __sincosf(ang, &sn, &cs);
                    float x1 = acc[mb][nb][r], x2 = acc[mb][nb + 2][r];
                    size_t base = (size_t)(b * 16 + h) * 262144
                                + (size_t)(s >> 5) * 4096 + (size_t)(s & 31) * 8;
                    Kp[base + (dd >> 3) * 256 + (dd & 7)] = f2bf(x1 * cs - x2 * sn);
                    Kp[base + (d2 >> 3) * 256 + (d2 & 7)] = f2bf(x2 * cs + x1 * sn);
                }
            }
        }
    } else if (seg == 3) {   // K-nope -> Kp chunk-major dims 64..127
        #pragma unroll
        for (int mb = 0; mb < 4; ++mb)
            #pragma unroll
            for (int nb = 0; nb < 4; ++nb) {
                const int m = m0 + wr * 64 + mb * 16 + quad * 4;
                const int n = nloc + wc * 64 + nb * 16 + li;
                const int d = 64 + (n & 63);
                const int b = m >> 11, sba = m & 2047;
                #pragma unroll
                for (int r = 0; r < 4; ++r) {
                    const int s = sba + r;
                    size_t o = (size_t)(b * 16 + h) * 262144 + (size_t)(s >> 5) * 4096
                             + (size_t)(d >> 3) * 256 + (size_t)(s & 31) * 8 + (d & 7);
                    Kp[o] = f2bf(acc[mb][nb][r]);
                }
            }
    } else {                 // V -> Vt chunk-major
        #pragma unroll
        for (int mb = 0; mb < 4; ++mb)
            #pragma unroll
            for (int nb = 0; nb < 4; ++nb) {
                const int m = m0 + wr * 64 + mb * 16 + quad * 4;   // s base, %4==0
                const int n = nloc + wc * 64 + nb * 16 + li;
                const int dn = n & 63;
                const int b = m >> 11, s = m & 2047;
                ushort4 st = make_ushort4(f2bf(acc[mb][nb][0]), f2bf(acc[mb][nb][1]),
                                          f2bf(acc[mb][nb][2]), f2bf(acc[mb][nb][3]));
                size_t o = (size_t)(b * 16 + h) * 131072 + (size_t)(s >> 5) * 2048
                         + (size_t)((s & 31) >> 3) * 512 + (size_t)dn * 8 + (s & 7);
                *(ushort4*)&Vt[o] = st;
            }
    }
}

// ---------------------------------------------------------------------------
// MFMA flash attention, causal, fixed-max softmax, SPLIT-K + PAIRING.
// (unchanged from round 8)
// ---------------------------------------------------------------------------
__global__ __launch_bounds__(256, 4) void attn_mfma(
    const unsigned short* __restrict__ Qp, const unsigned short* __restrict__ Kp,
    const unsigned short* __restrict__ Vt, unsigned short* __restrict__ y,
    float* __restrict__ O0, float* __restrict__ O1,
    float* __restrict__ l0, float* __restrict__ l1)
{
    __shared__ __align__(16) unsigned short Ks[2][4096];   // 2 x 8KB K tiles
    __shared__ __align__(16) unsigned short PT[4][640];    // per-wave P[16][40]

    const int t    = threadIdx.x;
    const int w    = t >> 6;
    const int lane = t & 63;
    const int li   = lane & 15;
    const int quad = lane >> 4;

    const int blk = blockIdx.x;
    const int xcd = blk & 7;
    const int g   = blk >> 3;            // 0..127
    const int bh  = xcd + 8 * (g & 3);   // 4 bh per xcd slot
    const int u   = g >> 2;              // 0..31
    const int p   = u >> 1;              // pair 0..15
    const int var = u & 1;
    const int b   = bh >> 4, h = bh & 15;

    const unsigned short* Kb = Kp + (size_t)bh * 262144;   // chunk-major tiles
    const unsigned short* Vb = Vt + (size_t)bh * 131072;

    short8 onesf;
    #pragma unroll
    for (int j = 0; j < 8; ++j) onesf[j] = (short)0x3F80;  // bf16 1.0

    unsigned short* Pw = &PT[w][0];

    auto run_seg = [&](int qt, int lo, int hi, int mode) {
        const int qbase  = qt * 64 + w * 16;
        const int lastkt = 2 * qt + (w >> 1);

        const unsigned short* Qb = Qp + ((size_t)bh * 2048 + qbase) * 128;
        short8 qf[4];
        #pragma unroll
        for (int kb = 0; kb < 4; ++kb)
            qf[kb] = *(const short8*)(Qb + (size_t)li * 128 + kb * 32 + quad * 8);

        floatx4 o0 = {0.f,0.f,0.f,0.f}, o1 = {0.f,0.f,0.f,0.f};
        floatx4 o2 = {0.f,0.f,0.f,0.f}, o3 = {0.f,0.f,0.f,0.f};
        floatx4 ol = {0.f,0.f,0.f,0.f};

        auto stageK = [&](int kt, int buf) {
            const unsigned short* gk = Kb + (size_t)kt * 4096 + w * 1024 + (size_t)lane * 8;
            GLL16(gk,       &Ks[buf][w * 1024]);
            GLL16(gk + 512, &Ks[buf][w * 1024 + 512]);
        };
        auto loadV = [&](int kt, short8 vf[4]) {
            const unsigned short* gv = Vb + (size_t)kt * 2048 + quad * 512 + li * 8;
            #pragma unroll
            for (int nb = 0; nb < 4; ++nb)
                vf[nb] = *(const short8*)(gv + nb * 128);
        };
        auto compute = [&](int kt, int buf, short8 vf[4], bool maskTile) {
            const int kbase = kt * 32;
            floatx4 s0 = {0.f,0.f,0.f,0.f}, s1 = {0.f,0.f,0.f,0.f};
            #pragma unroll
            for (int kb = 0; kb < 4; ++kb) {
                short8 k0 = *(const short8*)&Ks[buf][(kb * 4 + quad) * 256 + li * 8];
                short8 k1 = *(const short8*)&Ks[buf][(kb * 4 + quad) * 256 + (16 + li) * 8];
                s0 = __builtin_amdgcn_mfma_f32_16x16x32_bf16(qf[kb], k0, s0, 0, 0, 0);
                s1 = __builtin_amdgcn_mfma_f32_16x16x32_bf16(qf[kb], k1, s1, 0, 0, 0);
            }
            #pragma unroll
            for (int r = 0; r < 4; ++r) {
                const int i = quad * 4 + r;
                unsigned int u0 = __float_as_uint(__expf(s0[r])) >> 16;
                unsigned int u1 = __float_as_uint(__expf(s1[r])) >> 16;
                if (maskTile) {
                    const int qrow = qbase + i;
                    u0 = (kbase + li      <= qrow) ? u0 : 0u;
                    u1 = (kbase + 16 + li <= qrow) ? u1 : 0u;
                }
                Pw[i * 40 + li]      = (unsigned short)u0;
                Pw[i * 40 + 16 + li] = (unsigned short)u1;
            }
            short8 pf = *(const short8*)&Pw[li * 40 + quad * 8];

            ol = __builtin_amdgcn_mfma_f32_16x16x32_bf16(pf, onesf, ol, 0, 0, 0);
            o0 = __builtin_amdgcn_mfma_f32_16x16x32_bf16(pf, vf[0], o0, 0, 0, 0);
            o1 = __builtin_amdgcn_mfma_f32_16x16x32_bf16(pf, vf[1], o1, 0, 0, 0);
            o2 = __builtin_amdgcn_mfma_f32_16x16x32_bf16(pf, vf[2], o2, 0, 0, 0);
            o3 = __builtin_amdgcn_mfma_f32_16x16x32_bf16(pf, vf[3], o3, 0, 0, 0);
        };

        short8 vfa[4], vfb[4];
        __syncthreads();                 // protect Ks reuse across segments
        stageK(lo, 0);
        if (lo <= lastkt) loadV(lo, vfa);

        int kt = lo;
        while (true) {
            __syncthreads();             // Ks[buf] + current V landed
            if (kt + 1 < hi) {
                stageK(kt + 1, 1);
                if (kt + 1 <= lastkt) loadV(kt + 1, vfb);
            }
            if (kt <= lastkt) compute(kt, 0, vfa, kt == lastkt);
            ++kt; if (kt == hi) break;
            __syncthreads();
            if (kt + 1 < hi) {
                stageK(kt + 1, 0);
                if (kt + 1 <= lastkt) loadV(kt + 1, vfa);
            }
            if (kt <= lastkt) compute(kt, 1, vfb, kt == lastkt);
            ++kt; if (kt == hi) break;
        }

        if (mode == 0) {       // complete: normalize + write y
            unsigned short* yb2 = y + ((size_t)b * 2048 + qbase + quad * 4) * 1024 + h * 64 + li;
            #pragma unroll
            for (int r = 0; r < 4; ++r) {
                const float linv = 1.0f / ol[r];
                yb2[(size_t)r * 1024 + 0]  = f2bf(o0[r] * linv);
                yb2[(size_t)r * 1024 + 16] = f2bf(o1[r] * linv);
                yb2[(size_t)r * 1024 + 32] = f2bf(o2[r] * linv);
                yb2[(size_t)r * 1024 + 48] = f2bf(o3[r] * linv);
            }
        } else {               // partial: raw O (fp32) + row-sum l
            float* Op = (mode == 1) ? O0 : O1;
            float* lp = (mode == 1) ? l0 : l1;
            const int rowL = qbase - 1024 + quad * 4;   // qt >= 16 here
            float* ob = Op + ((size_t)bh * 1024 + rowL) * 64 + li;
            #pragma unroll
            for (int r = 0; r < 4; ++r) {
                ob[(size_t)r * 64 + 0]  = o0[r];
                ob[(size_t)r * 64 + 16] = o1[r];
                ob[(size_t)r * 64 + 32] = o2[r];
                ob[(size_t)r * 64 + 48] = o3[r];
            }
            if (li == 0) {
                #pragma unroll
                for (int r = 0; r < 4; ++r)
                    lp[bh * 1024 + rowL + r] = ol[r];
            }
        }
    };

    if (var == 0) {
        run_seg(p, 0, 2 * p + 2, 0);                 // lower q-tile, complete
        run_seg(31 - p, 0, 31 - 2 * p, 1);           // upper q-tile, k-prefix
    } else {
        run_seg(31 - p, 31 - 2 * p, 64 - 2 * p, 2);  // upper q-tile, k-suffix
    }
}

// ---------------------------------------------------------------------------
// Combine split-K partials: y(upper rows) = (O0+O1) / (l0+l1), bf16 out.
// ---------------------------------------------------------------------------
__global__ __launch_bounds__(256) void attn_combine(
    const float* __restrict__ O0, const float* __restrict__ O1,
    const float* __restrict__ l0, const float* __restrict__ l1,
    unsigned short* __restrict__ y)
{
    const int idx = blockIdx.x * 256 + threadIdx.x;   // 0 .. 524287
    const int c4  = idx & 15;
    const int row = (idx >> 4) & 1023;
    const int bh  = idx >> 14;
    const int b   = bh >> 4, h = bh & 15;

    const size_t o = ((size_t)bh * 1024 + row) * 64 + c4 * 4;
    float4 a  = *(const float4*)&O0[o];
    float4 c  = *(const float4*)&O1[o];
    const float linv = 1.0f / (l0[bh * 1024 + row] + l1[bh * 1024 + row]);

    ushort4 st = make_ushort4(f2bf((a.x + c.x) * linv), f2bf((a.y + c.y) * linv),
                              f2bf((a.z + c.z) * linv), f2bf((a.w + c.w) * linv));
    const size_t yo = ((size_t)b * 2048 + 1024 + row) * 1024 + h * 64 + c4 * 4;
    *(ushort4*)&y[yo] = st;
}

extern "C" void kernel_launch(void* const* d_in, const int* in_sizes, int n_in,
                              void* d_out, int out_size, void* d_ws, size_t ws_size,
                              hipStream_t stream)
{
    const float* x        = (const float*)d_in[0];
    const float* wq_down  = (const float*)d_in[1];
    const float* wk_rope  = (const float*)d_in[2];
    const float* wkv_down = (const float*)d_in[3];
    const float* wq_rope  = (const float*)d_in[4];
    const float* wq_up    = (const float*)d_in[5];
    const float* wk_up    = (const float*)d_in[6];
    const float* wv_up    = (const float*)d_in[7];
    const float* wo       = (const float*)d_in[8];
    float* out = (float*)d_out;

    char* wsb = (char*)d_ws;
    const size_t MB = 1u << 20;
    unsigned short* lat  = (unsigned short*)(wsb + 8 * MB);   // 6 MB  (4096x768: q|kr|kv)
    unsigned short* Qp   = (unsigned short*)(wsb + 14 * MB);  // 16 MB [b,h,s,128]
    unsigned short* Kp   = (unsigned short*)(wsb + 30 * MB);  // 16 MB chunk-major tiles
    unsigned short* Vt   = (unsigned short*)(wsb + 46 * MB);  // 8 MB  chunk-major tiles
    unsigned short* yb   = (unsigned short*)(wsb + 54 * MB);  // 8 MB  (4096x1024)
    unsigned short* wqd_b = (unsigned short*)(wsb + 62 * MB); // 512 KB each
    unsigned short* wkr_b = (unsigned short*)(wsb + 63 * MB);
    unsigned short* wkd_b = (unsigned short*)(wsb + 64 * MB);
    unsigned short* wqr_b = (unsigned short*)(wsb + 65 * MB);
    unsigned short* wqu_b = (unsigned short*)(wsb + 66 * MB);
    unsigned short* wku_b = (unsigned short*)(wsb + 67 * MB);
    unsigned short* wvu_b = (unsigned short*)(wsb + 68 * MB);
    unsigned short* wo_b  = (unsigned short*)(wsb + 69 * MB); // 2 MB
    float* O0p = (float*)(wsb + 71 * MB);                     // 8 MB (32x1024x64 fp32)
    float* O1p = (float*)(wsb + 79 * MB);                     // 8 MB
    float* l0p = (float*)(wsb + 87 * MB);                     // 128 KB
    float* l1p = (float*)(wsb + 87 * MB + (1u << 17));        // 128 KB -> ~87.3 MB total

    const float scale = 0.08838834764831845f;  // 1/sqrt(2*64), folded into Qp
    const int BIG = 1 << 30;
    dim3 blk(256);

    // ---- weight casts (one launch, 8 tensors; x cast fused into down-proj) ----
    CastArgs ca;
    ca.d[0] = { wq_down,  wqd_b,  262144 / 4 };
    ca.d[1] = { wk_rope,  wkr_b,  262144 / 4 };
    ca.d[2] = { wkv_down, wkd_b,  262144 / 4 };
    ca.d[3] = { wq_rope,  wqr_b,  262144 / 4 };
    ca.d[4] = { wq_up,    wqu_b,  262144 / 4 };
    ca.d[5] = { wk_up,    wku_b,  262144 / 4 };
    ca.d[6] = { wv_up,    wvu_b,  262144 / 4 };
    ca.d[7] = { wo,       wo_b,  1048576 / 4 };
    cast_bf16_multi<<<dim3(64, 8), blk, 0, stream>>>(ca);

    // ---- fused down projections (fp32 A, inline cast; 768 blocks) ----
    gemm64<3, true><<<dim3(12, 64), dim3(128), 0, stream>>>(
        x, 1024, wqd_b, wkr_b, wkd_b, 256, 1024, lat, 768, 1024, 1.f);

    // ---- fused Q/K/V up-projections (one launch, N=5120, 1280 blocks) ----
    gemm_qkv<<<dim3(40, 32), blk, 0, stream>>>(
        lat, wqr_b, wqu_b, wku_b, wvu_b, Qp, Kp, Vt, scale);

    // ---- attention: uniform split-K blocks (1024 x 4 waves) + combine ----
    attn_mfma<<<dim3(1024), blk, 0, stream>>>(Qp, Kp, Vt, yb, O0p, O1p, l0p, l1p);
    attn_combine<<<dim3(2048), blk, 0, stream>>>(O0p, O1p, l0p, l1p, yb);

    // ---- output projection (64x64 tiles, 1024 blocks = 4/CU), fp32 out ----
    gemm64<0, false><<<dim3(16, 64), dim3(128), 0, stream>>>(
        yb, 1024, wo_b, wo_b, wo_b, BIG, 1024, out, 1024, 1024, 1.f);
}

// Round 10
// 210.781 us; speedup vs baseline: 1.0208x; 1.0208x over previous
//
#include <hip/hip_runtime.h>
#include <hip/hip_bf16.h>
#include <math.h>

// ---------------------------------------------------------------------------
// B=2, S=2048, E=1024, R=256, H=16, Dqk=128 (rope64|nope64), Dv=64. BS=4096.
// Round 10: XOR-swizzled LDS tiles in all GEMM kernels. The m97-style layout
// (row*32 + quad*8) gives 8-way bank conflicts on every ds_read_b128 frag
// (lanes li -> byte li*64 -> banks {0,16} only). Swizzle: LDS slot (row,c)
// holds global chunk c ^ ((row>>1)&3) -> 2-way (free). GLL16-compatible:
// only the per-lane global column pick and the per-lane read chunk change.
// Attention/cast/combine unchanged from round 9.
// ---------------------------------------------------------------------------

typedef __attribute__((ext_vector_type(8))) short  short8;   // 8 bf16 (4 VGPR)
typedef __attribute__((ext_vector_type(4))) float  floatx4;  // MFMA C/D frag

static __device__ __forceinline__ unsigned short f2bf(float f) {
    __hip_bfloat16 h = __float2bfloat16(f);   // RNE
    return *reinterpret_cast<unsigned short*>(&h);
}

#define GLL16(gp, lp) __builtin_amdgcn_global_load_lds( \
    (const __attribute__((address_space(1))) void*)(gp), \
    (__attribute__((address_space(3))) void*)(lp), 16, 0, 0)

// ---------------------------------------------------------------------------
// fp32 -> bf16 casts, batched (8 weight tensors; x is cast in-GEMM)
// ---------------------------------------------------------------------------
struct CastDesc { const float* src; unsigned short* dst; int n4; };
struct CastArgs { CastDesc d[8]; };

__global__ __launch_bounds__(256) void cast_bf16_multi(CastArgs a)
{
    CastDesc dd = a.d[blockIdx.y];
    const int stride = gridDim.x * 256;
    for (int i = blockIdx.x * 256 + threadIdx.x; i < dd.n4; i += stride) {
        float4 v = ((const float4*)dd.src)[i];
        ushort4 o = make_ushort4(f2bf(v.x), f2bf(v.y), f2bf(v.z), f2bf(v.w));
        ((ushort4*)dd.dst)[i] = o;
    }
}

// ---------------------------------------------------------------------------
// 64x64-tile bf16 MFMA GEMM, 2 waves (each 32x64), BK=32, swizzled LDS.
// CVTA=false: A bf16 via global_load_lds. CVTA=true: A fp32, inline convert,
// ds_write_b128 to swizzled slots. C = A * B^T.
// MODE 0: fp32 store. MODE 3: bf16 row-major store, scaled.
// ---------------------------------------------------------------------------
template<int MODE, bool CVTA>
__global__ __launch_bounds__(128) void gemm64(
    const void* __restrict__ Ain, int lda,
    const unsigned short* __restrict__ B0,
    const unsigned short* __restrict__ B1,
    const unsigned short* __restrict__ B2, int nspan, int ldb,
    void* __restrict__ Cout, int ldc, int K, float oscale)
{
    __shared__ __align__(16) unsigned short As[64 * 32];
    __shared__ __align__(16) unsigned short Bs[64 * 32];

    const int t    = threadIdx.x;
    const int w    = t >> 6;
    const int lane = t & 63;
    const int li   = lane & 15;
    const int quad = lane >> 4;
    const int m0   = blockIdx.y * 64;
    const int n0   = blockIdx.x * 64;

    const unsigned short* Bp = (n0 < nspan) ? B0 : ((n0 < 2 * nspan) ? B1 : B2);
    const int nb0 = n0 % nspan;

    const int arow = m0 + w * 32 + (lane >> 2);
    const int acg  = (lane & 3) * 8;                              // unswizzled chunk col
    const int acs  = (((lane & 3) ^ ((lane >> 3) & 3))) * 8;      // swizzled chunk col
    const int cq   = (quad ^ ((li >> 1) & 3)) * 8;                // swizzled read chunk
    const unsigned short* gb = Bp + (size_t)(nb0 + w * 32 + (lane >> 2)) * ldb + acs;
    unsigned short* lA0 = &As[(w * 32) * 32];
    unsigned short* lA1 = &As[(w * 32 + 16) * 32];
    unsigned short* lB0 = &Bs[(w * 32) * 32];
    unsigned short* lB1 = &Bs[(w * 32 + 16) * 32];
    // CVTA: per-thread LDS write addresses (swizzled slot)
    unsigned short* wA0 = &As[(w * 32 + (lane >> 2)) * 32 + acs];
    unsigned short* wA1 = wA0 + 16 * 32;

    floatx4 acc[2][4];
    #pragma unroll
    for (int i = 0; i < 2; ++i)
        #pragma unroll
        for (int j = 0; j < 4; ++j)
            acc[i][j] = (floatx4){0.f, 0.f, 0.f, 0.f};

    for (int k0 = 0; k0 < K; k0 += 32) {
        if (CVTA) {
            const float* Af = (const float*)Ain;
            const float* ga0 = Af + (size_t)arow * lda + k0 + acg;
            float4 a00 = *(const float4*)(ga0);
            float4 a01 = *(const float4*)(ga0 + 4);
            float4 a10 = *(const float4*)(ga0 + (size_t)16 * lda);
            float4 a11 = *(const float4*)(ga0 + (size_t)16 * lda + 4);
            __syncthreads();
            GLL16(gb + k0,            lB0);
            GLL16(gb + 16 * ldb + k0, lB1);
            // write global chunk acg into swizzled slot (wA0 built from acs==
            // (acg^sw)): slot c_l holds global chunk c_l ^ sw  -> need the data
            // of chunk acg at slot acg^sw, which is exactly wA0 when we fetch acg.
            ushort4 p0 = make_ushort4(f2bf(a00.x), f2bf(a00.y), f2bf(a00.z), f2bf(a00.w));
            ushort4 p1 = make_ushort4(f2bf(a01.x), f2bf(a01.y), f2bf(a01.z), f2bf(a01.w));
            ushort4 p2 = make_ushort4(f2bf(a10.x), f2bf(a10.y), f2bf(a10.z), f2bf(a10.w));
            ushort4 p3 = make_ushort4(f2bf(a11.x), f2bf(a11.y), f2bf(a11.z), f2bf(a11.w));
            *(ushort4*)(wA0)     = p0;
            *(ushort4*)(wA0 + 4) = p1;
            *(ushort4*)(wA1)     = p2;
            *(ushort4*)(wA1 + 4) = p3;
            __syncthreads();
        } else {
            const unsigned short* Ab = (const unsigned short*)Ain;
            const unsigned short* ga = Ab + (size_t)arow * lda + acs;
            __syncthreads();
            GLL16(ga + k0,            lA0);
            GLL16(ga + 16 * lda + k0, lA1);
            GLL16(gb + k0,            lB0);
            GLL16(gb + 16 * ldb + k0, lB1);
            __syncthreads();
        }

        short8 af[2], bfr[4];
        #pragma unroll
        for (int mb = 0; mb < 2; ++mb)
            af[mb] = *(const short8*)&As[(w * 32 + mb * 16 + li) * 32 + cq];
        #pragma unroll
        for (int nb = 0; nb < 4; ++nb)
            bfr[nb] = *(const short8*)&Bs[(nb * 16 + li) * 32 + cq];
        #pragma unroll
        for (int mb = 0; mb < 2; ++mb)
            #pragma unroll
            for (int nb = 0; nb < 4; ++nb)
                acc[mb][nb] = __builtin_amdgcn_mfma_f32_16x16x32_bf16(
                    af[mb], bfr[nb], acc[mb][nb], 0, 0, 0);
    }

    if (MODE == 0) {
        float* C = (float*)Cout;
        #pragma unroll
        for (int mb = 0; mb < 2; ++mb)
            #pragma unroll
            for (int nb = 0; nb < 4; ++nb) {
                const int m = m0 + w * 32 + mb * 16 + quad * 4;
                const int n = n0 + nb * 16 + li;
                #pragma unroll
                for (int r = 0; r < 4; ++r)
                    C[(size_t)(m + r) * ldc + n] = acc[mb][nb][r] * oscale;
            }
    } else {
        unsigned short* C = (unsigned short*)Cout;
        #pragma unroll
        for (int mb = 0; mb < 2; ++mb)
            #pragma unroll
            for (int nb = 0; nb < 4; ++nb) {
                const int m = m0 + w * 32 + mb * 16 + quad * 4;
                const int n = n0 + nb * 16 + li;
                #pragma unroll
                for (int r = 0; r < 4; ++r)
                    C[(size_t)(m + r) * ldc + n] = f2bf(acc[mb][nb][r] * oscale);
            }
    }
}

// ---------------------------------------------------------------------------
// Fused Q/K/V up-projection GEMM (swizzled LDS). A = lat (4096 x 768).
// Virtual N = 5120 partitioned by n0 (see round-6 comment for the map).
// Kp tile layout: bh*262144 + (s>>5)*4096 + (d>>3)*256 + (s&31)*8 + (d&7).
// Vt tile layout: bh*131072 + (s>>5)*2048 + ((s&31)>>3)*512 + d*8 + (s&7).
// ---------------------------------------------------------------------------
__global__ __launch_bounds__(256) void gemm_qkv(
    const unsigned short* __restrict__ lat,
    const unsigned short* __restrict__ wqr, const unsigned short* __restrict__ wqu,
    const unsigned short* __restrict__ wku, const unsigned short* __restrict__ wvu,
    unsigned short* __restrict__ Qp, unsigned short* __restrict__ Kp,
    unsigned short* __restrict__ Vt, float qscale)
{
    __shared__ __align__(16) unsigned short As[128 * 32];
    __shared__ __align__(16) unsigned short Bs[128 * 32];

    const int t    = threadIdx.x;
    const int w    = t >> 6;
    const int lane = t & 63;
    const int li   = lane & 15;
    const int quad = lane >> 4;
    const int wr   = w >> 1, wc = w & 1;
    const int m0   = blockIdx.y * 128;
    const int n0   = blockIdx.x * 128;

    const unsigned short* Ap;
    const unsigned short* Bp;
    int nloc, seg;
    if (n0 < 1024)      { seg = 0; Ap = lat;       Bp = wqr; nloc = n0; }
    else if (n0 < 2048) { seg = 1; Ap = lat;       Bp = wqu; nloc = n0 - 1024; }
    else if (n0 < 3072) { seg = 2; Ap = lat + 256; Bp = wku; nloc = n0 - 2048; }
    else if (n0 < 4096) { seg = 3; Ap = lat + 512; Bp = wku; nloc = n0 - 3072; }
    else                { seg = 4; Ap = lat + 512; Bp = wvu; nloc = n0 - 4096; }
    const float oscale = (seg <= 1) ? qscale : 1.0f;

    const int acs = (((lane & 3) ^ ((lane >> 3) & 3))) * 8;   // swizzled chunk col
    const int cq  = (quad ^ ((li >> 1) & 3)) * 8;             // swizzled read chunk
    const unsigned short* ga = Ap + (size_t)(m0   + w * 32 + (lane >> 2)) * 768 + acs;
    const unsigned short* gb = Bp + (size_t)(nloc + w * 32 + (lane >> 2)) * 256 + acs;
    unsigned short* lA0 = &As[(w * 32) * 32];
    unsigned short* lA1 = &As[(w * 32 + 16) * 32];
    unsigned short* lB0 = &Bs[(w * 32) * 32];
    unsigned short* lB1 = &Bs[(w * 32 + 16) * 32];

    floatx4 acc[4][4];
    #pragma unroll
    for (int i = 0; i < 4; ++i)
        #pragma unroll
        for (int j = 0; j < 4; ++j)
            acc[i][j] = (floatx4){0.f, 0.f, 0.f, 0.f};

    for (int k0 = 0; k0 < 256; k0 += 32) {
        __syncthreads();
        GLL16(ga + k0,            lA0);
        GLL16(ga + 16 * 768 + k0, lA1);
        GLL16(gb + k0,            lB0);
        GLL16(gb + 16 * 256 + k0, lB1);
        __syncthreads();

        short8 af[4], bfr[4];
        #pragma unroll
        for (int mb = 0; mb < 4; ++mb)
            af[mb] = *(const short8*)&As[(wr * 64 + mb * 16 + li) * 32 + cq];
        #pragma unroll
        for (int nb = 0; nb < 4; ++nb)
            bfr[nb] = *(const short8*)&Bs[(wc * 64 + nb * 16 + li) * 32 + cq];
        #pragma unroll
        for (int mb = 0; mb < 4; ++mb)
            #pragma unroll
            for (int nb = 0; nb < 4; ++nb)
                acc[mb][nb] = __builtin_amdgcn_mfma_f32_16x16x32_bf16(
                    af[mb], bfr[nb], acc[mb][nb], 0, 0, 0);
    }

    const int h = ((nloc + wc * 64) >> 6) & 15;   // wave-uniform head

    if (seg == 0) {          // Q-rope -> Qp row-major dims 0..63
        float invf[2];
        #pragma unroll
        for (int nb = 0; nb < 2; ++nb)
            invf[nb] = exp2f((float)(nb * 16 + li) * -0.4152410118609203f);
        #pragma unroll
        for (int mb = 0; mb < 4; ++mb) {
            const int m = m0 + wr * 64 + mb * 16 + quad * 4;
            const int b = m >> 11, s = m & 2047;
            #pragma unroll
            for (int nb = 0; nb < 2; ++nb) {
                const int dd = nb * 16 + li;
                size_t o = ((size_t)(b * 16 + h) * 2048 + s) * 128 + dd;
                #pragma unroll
                for (int r = 0; r < 4; ++r) {
                    float ang = (float)(s + r) * invf[nb];
                    float sn, cs;
                    __sincosf(ang, &sn, &cs);
                    float x1 = acc[mb][nb][r], x2 = acc[mb][nb + 2][r];
                    Qp[o + (size_t)r * 128]      = f2bf((x1 * cs - x2 * sn) * oscale);
                    Qp[o + (size_t)r * 128 + 32] = f2bf((x2 * cs + x1 * sn) * oscale);
                }
            }
        }
    } else if (seg == 1) {   // Q-nope -> Qp row-major dims 64..127
        #pragma unroll
        for (int mb = 0; mb < 4; ++mb)
            #pragma unroll
            for (int nb = 0; nb < 4; ++nb) {
                const int m = m0 + wr * 64 + mb * 16 + quad * 4;
                const int n = nloc + wc * 64 + nb * 16 + li;
                const int dn = n & 63;
                const int b = m >> 11, s = m & 2047;
                size_t o = ((size_t)(b * 16 + h) * 2048 + s) * 128 + 64 + dn;
                #pragma unroll
                for (int r = 0; r < 4; ++r)
                    Qp[o + (size_t)r * 128] = f2bf(acc[mb][nb][r] * oscale);
            }
    } else if (seg == 2) {   // K-rope -> Kp chunk-major dims 0..63
        float invf[2];
        #pragma unroll
        for (int nb = 0; nb < 2; ++nb)
            invf[nb] = exp2f((float)(nb * 16 + li) * -0.4152410118609203f);
        #pragma unroll
        for (int mb = 0; mb < 4; ++mb) {
            const int m = m0 + wr * 64 + mb * 16 + quad * 4;
            const int b = m >> 11, sba = m & 2047;
            #pragma unroll
            for (int nb = 0; nb < 2; ++nb) {
                const int dd = nb * 16 + li;
                const int d2 = dd + 32;
                #pragma unroll
                for (int r = 0; r < 4; ++r) {
                    const int s = sba + r;
                    float ang = (float)s * invf[nb];
                    float sn, cs;
                    __sincosf(ang, &sn, &cs);
                    float x1 = acc[mb][nb][r], x2 = acc[mb][nb + 2][r];
                    size_t base = (size_t)(b * 16 + h) * 262144
                                + (size_t)(s >> 5) * 4096 + (size_t)(s & 31) * 8;
                    Kp[base + (dd >> 3) * 256 + (dd & 7)] = f2bf(x1 * cs - x2 * sn);
                    Kp[base + (d2 >> 3) * 256 + (d2 & 7)] = f2bf(x2 * cs + x1 * sn);
                }
            }
        }
    } else if (seg == 3) {   // K-nope -> Kp chunk-major dims 64..127
        #pragma unroll
        for (int mb = 0; mb < 4; ++mb)
            #pragma unroll
            for (int nb = 0; nb < 4; ++nb) {
                const int m = m0 + wr * 64 + mb * 16 + quad * 4;
                const int n = nloc + wc * 64 + nb * 16 + li;
                const int d = 64 + (n & 63);
                const int b = m >> 11, sba = m & 2047;
                #pragma unroll
                for (int r = 0; r < 4; ++r) {
                    const int s = sba + r;
                    size_t o = (size_t)(b * 16 + h) * 262144 + (size_t)(s >> 5) * 4096
                             + (size_t)(d >> 3) * 256 + (size_t)(s & 31) * 8 + (d & 7);
                    Kp[o] = f2bf(acc[mb][nb][r]);
                }
            }
    } else {                 // V -> Vt chunk-major
        #pragma unroll
        for (int mb = 0; mb < 4; ++mb)
            #pragma unroll
            for (int nb = 0; nb < 4; ++nb) {
                const int m = m0 + wr * 64 + mb * 16 + quad * 4;   // s base, %4==0
                const int n = nloc + wc * 64 + nb * 16 + li;
                const int dn = n & 63;
                const int b = m >> 11, s = m & 2047;
                ushort4 st = make_ushort4(f2bf(acc[mb][nb][0]), f2bf(acc[mb][nb][1]),
                                          f2bf(acc[mb][nb][2]), f2bf(acc[mb][nb][3]));
                size_t o = (size_t)(b * 16 + h) * 131072 + (size_t)(s >> 5) * 2048
                         + (size_t)((s & 31) >> 3) * 512 + (size_t)dn * 8 + (s & 7);
                *(ushort4*)&Vt[o] = st;
            }
    }
}

// ---------------------------------------------------------------------------
// MFMA flash attention, causal, fixed-max softmax, SPLIT-K + PAIRING.
// (unchanged from round 8)
// ---------------------------------------------------------------------------
__global__ __launch_bounds__(256, 4) void attn_mfma(
    const unsigned short* __restrict__ Qp, const unsigned short* __restrict__ Kp,
    const unsigned short* __restrict__ Vt, unsigned short* __restrict__ y,
    float* __restrict__ O0, float* __restrict__ O1,
    float* __restrict__ l0, float* __restrict__ l1)
{
    __shared__ __align__(16) unsigned short Ks[2][4096];   // 2 x 8KB K tiles
    __shared__ __align__(16) unsigned short PT[4][640];    // per-wave P[16][40]

    const int t    = threadIdx.x;
    const int w    = t >> 6;
    const int lane = t & 63;
    const int li   = lane & 15;
    const int quad = lane >> 4;

    const int blk = blockIdx.x;
    const int xcd = blk & 7;
    const int g   = blk >> 3;            // 0..127
    const int bh  = xcd + 8 * (g & 3);   // 4 bh per xcd slot
    const int u   = g >> 2;              // 0..31
    const int p   = u >> 1;              // pair 0..15
    const int var = u & 1;
    const int b   = bh >> 4, h = bh & 15;

    const unsigned short* Kb = Kp + (size_t)bh * 262144;   // chunk-major tiles
    const unsigned short* Vb = Vt + (size_t)bh * 131072;

    short8 onesf;
    #pragma unroll
    for (int j = 0; j < 8; ++j) onesf[j] = (short)0x3F80;  // bf16 1.0

    unsigned short* Pw = &PT[w][0];

    auto run_seg = [&](int qt, int lo, int hi, int mode) {
        const int qbase  = qt * 64 + w * 16;
        const int lastkt = 2 * qt + (w >> 1);

        const unsigned short* Qb = Qp + ((size_t)bh * 2048 + qbase) * 128;
        short8 qf[4];
        #pragma unroll
        for (int kb = 0; kb < 4; ++kb)
            qf[kb] = *(const short8*)(Qb + (size_t)li * 128 + kb * 32 + quad * 8);

        floatx4 o0 = {0.f,0.f,0.f,0.f}, o1 = {0.f,0.f,0.f,0.f};
        floatx4 o2 = {0.f,0.f,0.f,0.f}, o3 = {0.f,0.f,0.f,0.f};
        floatx4 ol = {0.f,0.f,0.f,0.f};

        auto stageK = [&](int kt, int buf) {
            const unsigned short* gk = Kb + (size_t)kt * 4096 + w * 1024 + (size_t)lane * 8;
            GLL16(gk,       &Ks[buf][w * 1024]);
            GLL16(gk + 512, &Ks[buf][w * 1024 + 512]);
        };
        auto loadV = [&](int kt, short8 vf[4]) {
            const unsigned short* gv = Vb + (size_t)kt * 2048 + quad * 512 + li * 8;
            #pragma unroll
            for (int nb = 0; nb < 4; ++nb)
                vf[nb] = *(const short8*)(gv + nb * 128);
        };
        auto compute = [&](int kt, int buf, short8 vf[4], bool maskTile) {
            const int kbase = kt * 32;
            floatx4 s0 = {0.f,0.f,0.f,0.f}, s1 = {0.f,0.f,0.f,0.f};
            #pragma unroll
            for (int kb = 0; kb < 4; ++kb) {
                short8 k0 = *(const short8*)&Ks[buf][(kb * 4 + quad) * 256 + li * 8];
                short8 k1 = *(const short8*)&Ks[buf][(kb * 4 + quad) * 256 + (16 + li) * 8];
                s0 = __builtin_amdgcn_mfma_f32_16x16x32_bf16(qf[kb], k0, s0, 0, 0, 0);
                s1 = __builtin_amdgcn_mfma_f32_16x16x32_bf16(qf[kb], k1, s1, 0, 0, 0);
            }
            #pragma unroll
            for (int r = 0; r < 4; ++r) {
                const int i = quad * 4 + r;
                unsigned int u0 = __float_as_uint(__expf(s0[r])) >> 16;
                unsigned int u1 = __float_as_uint(__expf(s1[r])) >> 16;
                if (maskTile) {
                    const int qrow = qbase + i;
                    u0 = (kbase + li      <= qrow) ? u0 : 0u;
                    u1 = (kbase + 16 + li <= qrow) ? u1 : 0u;
                }
                Pw[i * 40 + li]      = (unsigned short)u0;
                Pw[i * 40 + 16 + li] = (unsigned short)u1;
            }
            short8 pf = *(const short8*)&Pw[li * 40 + quad * 8];

            ol = __builtin_amdgcn_mfma_f32_16x16x32_bf16(pf, onesf, ol, 0, 0, 0);
            o0 = __builtin_amdgcn_mfma_f32_16x16x32_bf16(pf, vf[0], o0, 0, 0, 0);
            o1 = __builtin_amdgcn_mfma_f32_16x16x32_bf16(pf, vf[1], o1, 0, 0, 0);
            o2 = __builtin_amdgcn_mfma_f32_16x16x32_bf16(pf, vf[2], o2, 0, 0, 0);
            o3 = __builtin_amdgcn_mfma_f32_16x16x32_bf16(pf, vf[3], o3, 0, 0, 0);
        };

        short8 vfa[4], vfb[4];
        __syncthreads();                 // protect Ks reuse across segments
        stageK(lo, 0);
        if (lo <= lastkt) loadV(lo, vfa);

        int kt = lo;
        while (true) {
            __syncthreads();             // Ks[buf] + current V landed
            if (kt + 1 < hi) {
                stageK(kt + 1, 1);
                if (kt + 1 <= lastkt) loadV(kt + 1, vfb);
            }
            if (kt <= lastkt) compute(kt, 0, vfa, kt == lastkt);
            ++kt; if (kt == hi) break;
            __syncthreads();
            if (kt + 1 < hi) {
                stageK(kt + 1, 0);
                if (kt + 1 <= lastkt) loadV(kt + 1, vfa);
            }
            if (kt <= lastkt) compute(kt, 1, vfb, kt == lastkt);
            ++kt; if (kt == hi) break;
        }

        if (mode == 0) {       // complete: normalize + write y
            unsigned short* yb2 = y + ((size_t)b * 2048 + qbase + quad * 4) * 1024 + h * 64 + li;
            #pragma unroll
            for (int r = 0; r < 4; ++r) {
                const float linv = 1.0f / ol[r];
                yb2[(size_t)r * 1024 + 0]  = f2bf(o0[r] * linv);
                yb2[(size_t)r * 1024 + 16] = f2bf(o1[r] * linv);
                yb2[(size_t)r * 1024 + 32] = f2bf(o2[r] * linv);
                yb2[(size_t)r * 1024 + 48] = f2bf(o3[r] * linv);
            }
        } else {               // partial: raw O (fp32) + row-sum l
            float* Op = (mode == 1) ? O0 : O1;
            float* lp = (mode == 1) ? l0 : l1;
            const int rowL = qbase - 1024 + quad * 4;   // qt >= 16 here
            float* ob = Op + ((size_t)bh * 1024 + rowL) * 64 + li;
            #pragma unroll
            for (int r = 0; r < 4; ++r) {
                ob[(size_t)r * 64 + 0]  = o0[r];
                ob[(size_t)r * 64 + 16] = o1[r];
                ob[(size_t)r * 64 + 32] = o2[r];
                ob[(size_t)r * 64 + 48] = o3[r];
            }
            if (li == 0) {
                #pragma unroll
                for (int r = 0; r < 4; ++r)
                    lp[bh * 1024 + rowL + r] = ol[r];
            }
        }
    };

    if (var == 0) {
        run_seg(p, 0, 2 * p + 2, 0);                 // lower q-tile, complete
        run_seg(31 - p, 0, 31 - 2 * p, 1);           // upper q-tile, k-prefix
    } else {
        run_seg(31 - p, 31 - 2 * p, 64 - 2 * p, 2);  // upper q-tile, k-suffix
    }
}

// ---------------------------------------------------------------------------
// Combine split-K partials: y(upper rows) = (O0+O1) / (l0+l1), bf16 out.
// ---------------------------------------------------------------------------
__global__ __launch_bounds__(256) void attn_combine(
    const float* __restrict__ O0, const float* __restrict__ O1,
    const float* __restrict__ l0, const float* __restrict__ l1,
    unsigned short* __restrict__ y)
{
    const int idx = blockIdx.x * 256 + threadIdx.x;   // 0 .. 524287
    const int c4  = idx & 15;
    const int row = (idx >> 4) & 1023;
    const int bh  = idx >> 14;
    const int b   = bh >> 4, h = bh & 15;

    const size_t o = ((size_t)bh * 1024 + row) * 64 + c4 * 4;
    float4 a  = *(const float4*)&O0[o];
    float4 c  = *(const float4*)&O1[o];
    const float linv = 1.0f / (l0[bh * 1024 + row] + l1[bh * 1024 + row]);

    ushort4 st = make_ushort4(f2bf((a.x + c.x) * linv), f2bf((a.y + c.y) * linv),
                              f2bf((a.z + c.z) * linv), f2bf((a.w + c.w) * linv));
    const size_t yo = ((size_t)b * 2048 + 1024 + row) * 1024 + h * 64 + c4 * 4;
    *(ushort4*)&y[yo] = st;
}

extern "C" void kernel_launch(void* const* d_in, const int* in_sizes, int n_in,
                              void* d_out, int out_size, void* d_ws, size_t ws_size,
                              hipStream_t stream)
{
    const float* x        = (const float*)d_in[0];
    const float* wq_down  = (const float*)d_in[1];
    const float* wk_rope  = (const float*)d_in[2];
    const float* wkv_down = (const float*)d_in[3];
    const float* wq_rope  = (const float*)d_in[4];
    const float* wq_up    = (const float*)d_in[5];
    const float* wk_up    = (const float*)d_in[6];
    const float* wv_up    = (const float*)d_in[7];
    const float* wo       = (const float*)d_in[8];
    float* out = (float*)d_out;

    char* wsb = (char*)d_ws;
    const size_t MB = 1u << 20;
    unsigned short* lat  = (unsigned short*)(wsb + 8 * MB);   // 6 MB  (4096x768: q|kr|kv)
    unsigned short* Qp   = (unsigned short*)(wsb + 14 * MB);  // 16 MB [b,h,s,128]
    unsigned short* Kp   = (unsigned short*)(wsb + 30 * MB);  // 16 MB chunk-major tiles
    unsigned short* Vt   = (unsigned short*)(wsb + 46 * MB);  // 8 MB  chunk-major tiles
    unsigned short* yb   = (unsigned short*)(wsb + 54 * MB);  // 8 MB  (4096x1024)
    unsigned short* wqd_b = (unsigned short*)(wsb + 62 * MB); // 512 KB each
    unsigned short* wkr_b = (unsigned short*)(wsb + 63 * MB);
    unsigned short* wkd_b = (unsigned short*)(wsb + 64 * MB);
    unsigned short* wqr_b = (unsigned short*)(wsb + 65 * MB);
    unsigned short* wqu_b = (unsigned short*)(wsb + 66 * MB);
    unsigned short* wku_b = (unsigned short*)(wsb + 67 * MB);
    unsigned short* wvu_b = (unsigned short*)(wsb + 68 * MB);
    unsigned short* wo_b  = (unsigned short*)(wsb + 69 * MB); // 2 MB
    float* O0p = (float*)(wsb + 71 * MB);                     // 8 MB (32x1024x64 fp32)
    float* O1p = (float*)(wsb + 79 * MB);                     // 8 MB
    float* l0p = (float*)(wsb + 87 * MB);                     // 128 KB
    float* l1p = (float*)(wsb + 87 * MB + (1u << 17));        // 128 KB -> ~87.3 MB total

    const float scale = 0.08838834764831845f;  // 1/sqrt(2*64), folded into Qp
    const int BIG = 1 << 30;
    dim3 blk(256);

    // ---- weight casts (one launch, 8 tensors; x cast fused into down-proj) ----
    CastArgs ca;
    ca.d[0] = { wq_down,  wqd_b,  262144 / 4 };
    ca.d[1] = { wk_rope,  wkr_b,  262144 / 4 };
    ca.d[2] = { wkv_down, wkd_b,  262144 / 4 };
    ca.d[3] = { wq_rope,  wqr_b,  262144 / 4 };
    ca.d[4] = { wq_up,    wqu_b,  262144 / 4 };
    ca.d[5] = { wk_up,    wku_b,  262144 / 4 };
    ca.d[6] = { wv_up,    wvu_b,  262144 / 4 };
    ca.d[7] = { wo,       wo_b,  1048576 / 4 };
    cast_bf16_multi<<<dim3(64, 8), blk, 0, stream>>>(ca);

    // ---- fused down projections (fp32 A, inline cast; 768 blocks) ----
    gemm64<3, true><<<dim3(12, 64), dim3(128), 0, stream>>>(
        x, 1024, wqd_b, wkr_b, wkd_b, 256, 1024, lat, 768, 1024, 1.f);

    // ---- fused Q/K/V up-projections (one launch, N=5120, 1280 blocks) ----
    gemm_qkv<<<dim3(40, 32), blk, 0, stream>>>(
        lat, wqr_b, wqu_b, wku_b, wvu_b, Qp, Kp, Vt, scale);

    // ---- attention: uniform split-K blocks (1024 x 4 waves) + combine ----
    attn_mfma<<<dim3(1024), blk, 0, stream>>>(Qp, Kp, Vt, yb, O0p, O1p, l0p, l1p);
    attn_combine<<<dim3(2048), blk, 0, stream>>>(O0p, O1p, l0p, l1p, yb);

    // ---- output projection (64x64 tiles, 1024 blocks = 4/CU), fp32 out ----
    gemm64<0, false><<<dim3(16, 64), dim3(128), 0, stream>>>(
        yb, 1024, wo_b, wo_b, wo_b, BIG, 1024, out, 1024, 1024, 1.f);
}